// Round 7
// baseline (395.498 us; speedup 1.0000x reference)
//
#include <hip/hip_runtime.h>

#define DEV __device__ __forceinline__

typedef __attribute__((ext_vector_type(8))) short bf16x8;
typedef __attribute__((ext_vector_type(4))) float f32x4;

DEV float4 ld4(const float* p){ return *reinterpret_cast<const float4*>(p); }

DEV unsigned short f2bf(float f){
    union { float f; unsigned u; } v; v.f = f;
    unsigned r = v.u + 0x7fffu + ((v.u >> 16) & 1u);   // round-to-nearest-even
    return (unsigned short)(r >> 16);
}
DEV float bf2f(unsigned short s){
    union { unsigned u; float f; } v; v.u = ((unsigned)s) << 16;
    return v.f;
}

// bijective XCD-chunk swizzle (m204)
DEV int xcd_swizzle(int orig, int nwg){
    int q = nwg >> 3, r = nwg & 7;
    int x = orig & 7, i = orig >> 3;
    return (x < r ? x*(q+1) : r*(q+1) + (x-r)*q) + i;
}

// ---------------- inverse kernel-map build ----------------
__global__ __launch_bounds__(256)
void inv_init(int* __restrict__ inv, long n, int defv){
    long i = (long)blockIdx.x*256 + threadIdx.x;
    if (i < n) inv[i] = defv;
}

__global__ __launch_bounds__(256)
void inv_build(const int* __restrict__ inK, const int* __restrict__ outK,
               int* __restrict__ inv, int M, int n_out){
    int k = blockIdx.y;
    int m = blockIdx.x*256 + threadIdx.x;
    if (m >= M) return;
    int o = outK[(long)k*M + m];
    if (o != n_out) inv[(long)k*n_out + o] = inK[(long)k*M + m];  // o unique per offset
}

// zero the sentinel rows (row n_out) of the bf16 feature buffers
__global__ __launch_bounds__(256)
void zero_rows(unsigned short* A, unsigned short* B, unsigned short* C,
               unsigned short* D, unsigned short* E, int n_out){
    int t = threadIdx.x;
    if (t < 64)       A[(long)n_out*64 + t] = 0;
    else if (t < 80)  B[(long)n_out*16 + (t-64)] = 0;
    else if (t < 144) C[(long)n_out*64 + (t-80)] = 0;
    else if (t < 160) D[(long)n_out*16 + (t-144)] = 0;
    else if (t < 176) E[(long)n_out*16 + (t-160)] = 0;
}

// ---------------- W -> fragment-layout bf16 conversion ----------------
__global__ __launch_bounds__(256)
void wfrag_unpaired(const float* __restrict__ W, unsigned short* __restrict__ F,
                    int KC, int NT, int CIN, int CR, int total){
    int idx = blockIdx.x*256 + threadIdx.x;
    if (idx >= total) return;
    int j = idx & 7, l = (idx >> 3) & 63, rest = idx >> 9;
    int nt = rest % NT, cc = rest / NT;
    int k = cc / KC, kc = cc % KC;
    int g = l >> 4, c = l & 15;
    int cin = kc*32 + g*8 + j, cout = nt*16 + c;
    float v = (cout < CR) ? W[((long)k*CIN + cin)*CR + cout] : 0.f;
    F[idx] = f2bf(v);
}

__global__ __launch_bounds__(256)
void wfrag_paired(const float* __restrict__ W, unsigned short* __restrict__ F,
                  int NKr, int NT, int CR, int total){
    int idx = blockIdx.x*256 + threadIdx.x;
    if (idx >= total) return;
    int j = idx & 7, l = (idx >> 3) & 63, rest = idx >> 9;
    int nt = rest % NT, cc = rest / NT;
    int g = l >> 4, c = l & 15;
    int koff = 2*cc + (g >> 1);
    int cin = (g & 1)*8 + j, cout = nt*16 + c;
    float v = (koff < NKr && cout < CR) ? W[((long)koff*16 + cin)*CR + cout] : 0.f;
    F[idx] = f2bf(v);
}

// ---------------- gather MFMA conv: register-batched load pipeline ----------------
// MODE 0: inv-gather, NK offsets x KC K32-chunks, bf16 X rows of RB bytes (sentinel n_out -> zero row)
// MODE 1: paired inv-gather (CIN=16): NK chunk-pairs, offset = 2c+(g>>1), inv pad row 27 = sentinel
// MODE 4: conv1: A from TWO fp32 arrays (kc<2: xF else ctxF), sentinel -1, clamp+cndmask (n_in > n_out!)
// Per batch of GB offsets: [issue all feature loads] | [issue next idx loads] | [convert+W+MFMA]
template<int MODE, int NK, int GB, int KC, int NT, int RB, bool RELU, int RESBASE,
         bool OUTBF16, int YS, int CB, int CR, int WPE>
__global__ __launch_bounds__(256, WPE)
void mfma_gather(const void* __restrict__ Xv,
                 const float* __restrict__ xF, const float* __restrict__ cF,
                 const unsigned short* __restrict__ Wf, const int* __restrict__ inv,
                 const float* __restrict__ bias, const unsigned short* __restrict__ RES,
                 void* __restrict__ Yv, int n_out)
{
    const int bid = xcd_swizzle(blockIdx.x, gridDim.x);
    const int lane = threadIdx.x & 63, wave = threadIdx.x >> 6;
    const int jbase = (bid*4 + wave)*32;      // 32 rows per wave
    if (jbase >= n_out) return;
    const int r = lane & 15, g = lane >> 4;
    const int jc0 = min(jbase + r, n_out-1), jc1 = min(jbase + 16 + r, n_out-1);
    const char* X = (const char*)Xv;
    const bf16x8* __restrict__ WF = (const bf16x8*)Wf;
    const bf16x8 az = {0,0,0,0,0,0,0,0};
    f32x4 acc0[NT], acc1[NT];
    #pragma unroll
    for (int nt=0; nt<NT; ++nt){ acc0[nt] = f32x4{0,0,0,0}; acc1[nt] = f32x4{0,0,0,0}; }

    constexpr int NB = (NK + GB - 1) / GB;
    constexpr int F4N = (MODE == 4) ? GB*KC : 1;

    int bi0[GB], bi1[GB];
    #pragma unroll
    for (int kk=0; kk<GB; ++kk){
        if (kk < NK) {
            const long ko = (MODE == 1) ? (long)(2*kk + (g>>1))*n_out : (long)kk*n_out;
            bi0[kk] = inv[ko + jc0];
            bi1[kk] = inv[ko + jc1];
        }
    }

    #pragma unroll
    for (int nb=0; nb<NB; ++nb){
        // ---- phase 1: issue all feature loads of batch nb ----
        bf16x8 a0[GB][KC], a1[GB][KC];
        float4 flo0[F4N], fhi0[F4N], flo1[F4N], fhi1[F4N];
        #pragma unroll
        for (int kk=0; kk<GB; ++kk){
            if (nb*GB + kk < NK) {
                #pragma unroll
                for (int kc=0; kc<KC; ++kc){
                    if constexpr (MODE == 4) {
                        int bb0 = max(bi0[kk], 0), bb1 = max(bi1[kk], 0);
                        const float* s0 = (kc < 2) ? (xF + (long)bb0*64 + kc*32 + g*8)
                                                   : (cF + (long)bb0*64 + (kc-2)*32 + g*8);
                        const float* s1 = (kc < 2) ? (xF + (long)bb1*64 + kc*32 + g*8)
                                                   : (cF + (long)bb1*64 + (kc-2)*32 + g*8);
                        flo0[kk*KC+kc] = ld4(s0); fhi0[kk*KC+kc] = ld4(s0+4);
                        flo1[kk*KC+kc] = ld4(s1); fhi1[kk*KC+kc] = ld4(s1+4);
                    } else if constexpr (MODE == 1) {
                        a0[kk][kc] = *(const bf16x8*)(X + (long)bi0[kk]*RB + (g&1)*16);
                        a1[kk][kc] = *(const bf16x8*)(X + (long)bi1[kk]*RB + (g&1)*16);
                    } else {
                        a0[kk][kc] = *(const bf16x8*)(X + (long)bi0[kk]*RB + kc*64 + g*16);
                        a1[kk][kc] = *(const bf16x8*)(X + (long)bi1[kk]*RB + kc*64 + g*16);
                    }
                }
            }
        }
        __builtin_amdgcn_sched_barrier(0);

        // ---- phase 2: issue next batch's index loads (stay in flight across MFMAs) ----
        int ni0[GB], ni1[GB];
        if (nb + 1 < NB) {
            #pragma unroll
            for (int kk=0; kk<GB; ++kk){
                const int k = (nb+1)*GB + kk;
                if (k < NK) {
                    const long ko = (MODE == 1) ? (long)(2*k + (g>>1))*n_out : (long)k*n_out;
                    ni0[kk] = inv[ko + jc0];
                    ni1[kk] = inv[ko + jc1];
                }
            }
        }
        __builtin_amdgcn_sched_barrier(0);

        // ---- phase 3: convert (MODE 4) + W loads + MFMAs for batch nb ----
        #pragma unroll
        for (int kk=0; kk<GB; ++kk){
            if (nb*GB + kk < NK) {
                const int k = nb*GB + kk;
                #pragma unroll
                for (int kc=0; kc<KC; ++kc){
                    bf16x8 va0, va1;
                    if constexpr (MODE == 4) {
                        float4 lo = flo0[kk*KC+kc], hi = fhi0[kk*KC+kc];
                        va0[0]=(short)f2bf(lo.x); va0[1]=(short)f2bf(lo.y);
                        va0[2]=(short)f2bf(lo.z); va0[3]=(short)f2bf(lo.w);
                        va0[4]=(short)f2bf(hi.x); va0[5]=(short)f2bf(hi.y);
                        va0[6]=(short)f2bf(hi.z); va0[7]=(short)f2bf(hi.w);
                        lo = flo1[kk*KC+kc]; hi = fhi1[kk*KC+kc];
                        va1[0]=(short)f2bf(lo.x); va1[1]=(short)f2bf(lo.y);
                        va1[2]=(short)f2bf(lo.z); va1[3]=(short)f2bf(lo.w);
                        va1[4]=(short)f2bf(hi.x); va1[5]=(short)f2bf(hi.y);
                        va1[6]=(short)f2bf(hi.z); va1[7]=(short)f2bf(hi.w);
                        va0 = (bi0[kk] >= 0) ? va0 : az;
                        va1 = (bi1[kk] >= 0) ? va1 : az;
                    } else {
                        va0 = a0[kk][kc]; va1 = a1[kk][kc];
                    }
                    #pragma unroll
                    for (int nt=0; nt<NT; ++nt){
                        bf16x8 w = WF[((long)(k*KC+kc)*NT + nt)*64 + lane];
                        acc0[nt] = __builtin_amdgcn_mfma_f32_16x16x32_bf16(va0, w, acc0[nt], 0, 0, 0);
                        acc1[nt] = __builtin_amdgcn_mfma_f32_16x16x32_bf16(va1, w, acc1[nt], 0, 0, 0);
                    }
                }
            }
        }
        // ---- rotate index registers ----
        if (nb + 1 < NB) {
            #pragma unroll
            for (int kk=0; kk<GB; ++kk){ bi0[kk] = ni0[kk]; bi1[kk] = ni1[kk]; }
        }
    }

    // epilogue: D layout col = lane&15, row = (lane>>4)*4 + q  [m89-verified]
    float bi[NT];
    #pragma unroll
    for (int nt=0; nt<NT; ++nt){
        int c = nt*16 + r;
        bi[nt] = (c < CR) ? bias[c] : 0.f;
    }
    #pragma unroll
    for (int q=0; q<4; ++q){
        int row = jbase + g*4 + q;
        if (row < n_out){
            #pragma unroll
            for (int nt=0; nt<NT; ++nt){
                int c = nt*16 + r;
                float v = acc0[nt][q] + bi[nt];
                if constexpr (RESBASE >= 0) v += bf2f(RES[(long)row*64 + RESBASE + c]);
                if constexpr (RELU) v = fmaxf(v, 0.f);
                if constexpr (OUTBF16) ((unsigned short*)Yv)[(long)row*YS + CB + c] = f2bf(v);
                else if (c < CR)       ((float*)Yv)[(long)row*YS + CB + c] = v;
            }
        }
    }
    #pragma unroll
    for (int q=0; q<4; ++q){
        int row = jbase + 16 + g*4 + q;
        if (row < n_out){
            #pragma unroll
            for (int nt=0; nt<NT; ++nt){
                int c = nt*16 + r;
                float v = acc1[nt][q] + bi[nt];
                if constexpr (RESBASE >= 0) v += bf2f(RES[(long)row*64 + RESBASE + c]);
                if constexpr (RELU) v = fmaxf(v, 0.f);
                if constexpr (OUTBF16) ((unsigned short*)Yv)[(long)row*YS + CB + c] = f2bf(v);
                else if (c < CR)       ((float*)Yv)[(long)row*YS + CB + c] = v;
            }
        }
    }
}

// ---------------- identity-mode MFMA (dense 1x1s) ----------------
// MODE 2: identity (CIN=64); MODE 3: identity-paired (CIN=16), groups >=2 zero
template<int MODE, int NT, int RB, bool RELU, int RESBASE,
         bool OUTBF16, int YS, int CB, int CR>
__global__ __launch_bounds__(256)
void mfma_dense(const void* __restrict__ Xv,
                const unsigned short* __restrict__ Wf,
                const float* __restrict__ bias, const unsigned short* __restrict__ RES,
                void* __restrict__ Yv, int n_out)
{
    const int lane = threadIdx.x & 63, wave = threadIdx.x >> 6;
    const int jbase = (blockIdx.x*4 + wave)*16;
    if (jbase >= n_out) return;
    const int r = lane & 15, g = lane >> 4;
    const int jrow = jbase + r;
    const bool rowok = jrow < n_out;
    const char* X = (const char*)Xv;
    const bf16x8* __restrict__ WF = (const bf16x8*)Wf;
    const bf16x8 az = {0,0,0,0,0,0,0,0};
    f32x4 acc[NT];
    #pragma unroll
    for (int nt=0; nt<NT; ++nt) acc[nt] = f32x4{0,0,0,0};

    if constexpr (MODE == 2) {
        #pragma unroll
        for (int kc=0; kc<2; ++kc){
            bf16x8 a = az;
            if (rowok) a = *(const bf16x8*)(X + (long)jrow*RB + kc*64 + g*16);
            #pragma unroll
            for (int nt=0; nt<NT; ++nt){
                bf16x8 w = WF[((long)kc*NT + nt)*64 + lane];
                acc[nt] = __builtin_amdgcn_mfma_f32_16x16x32_bf16(a, w, acc[nt], 0, 0, 0);
            }
        }
    } else {
        bf16x8 a = az;
        if (rowok && g < 2) a = *(const bf16x8*)(X + (long)jrow*RB + (g&1)*16);
        #pragma unroll
        for (int nt=0; nt<NT; ++nt){
            bf16x8 w = WF[nt*64 + lane];
            acc[nt] = __builtin_amdgcn_mfma_f32_16x16x32_bf16(a, w, acc[nt], 0, 0, 0);
        }
    }

    float bi[NT];
    #pragma unroll
    for (int nt=0; nt<NT; ++nt){
        int c = nt*16 + r;
        bi[nt] = (c < CR) ? bias[c] : 0.f;
    }
    #pragma unroll
    for (int q=0; q<4; ++q){
        int row = jbase + g*4 + q;
        if (row < n_out){
            #pragma unroll
            for (int nt=0; nt<NT; ++nt){
                int c = nt*16 + r;
                float v = acc[nt][q] + bi[nt];
                if constexpr (RESBASE >= 0) v += bf2f(RES[(long)row*64 + RESBASE + c]);
                if constexpr (RELU) v = fmaxf(v, 0.f);
                if constexpr (OUTBF16) ((unsigned short*)Yv)[(long)row*YS + CB + c] = f2bf(v);
                else if (c < CR)       ((float*)Yv)[(long)row*YS + CB + c] = v;
            }
        }
    }
}

extern "C" void kernel_launch(void* const* d_in, const int* in_sizes, int n_in_cnt,
                              void* d_out, int out_size, void* d_ws, size_t ws_size,
                              hipStream_t stream)
{
    const float* xF   = (const float*)d_in[0];
    const float* ctxF = (const float*)d_in[1];
    const float* W1   = (const float*)d_in[2];
    const float* b1   = (const float*)d_in[3];
    const float* Wr00 = (const float*)d_in[4];
    const float* br00 = (const float*)d_in[5];
    const float* Wr01 = (const float*)d_in[6];
    const float* br01 = (const float*)d_in[7];
    const float* Wr10 = (const float*)d_in[8];
    const float* br10 = (const float*)d_in[9];
    const float* Wr11 = (const float*)d_in[10];
    const float* br11 = (const float*)d_in[11];
    const float* Wr12 = (const float*)d_in[12];
    const float* br12 = (const float*)d_in[13];
    const float* W2   = (const float*)d_in[14];
    const float* b2   = (const float*)d_in[15];
    const int* in1  = (const int*)d_in[16];
    const int* out1 = (const int*)d_in[17];
    const int* in3  = (const int*)d_in[18];
    const int* out3 = (const int*)d_in[19];

    const int n_out = out_size / 8;          // CL = 8
    const int M1 = in_sizes[16] / 8;
    const int M3 = in_sizes[18] / 27;

    char* p = (char*)d_ws;
    int* inv3 = (int*)p;                 p += (size_t)28*n_out*4;   // 27 built + 1 pad row
    int* inv1 = (int*)p;                 p += (size_t)8*n_out*4;
    unsigned short* A = (unsigned short*)p;  p += (size_t)(n_out+1)*64*2;
    unsigned short* B = (unsigned short*)p;  p += (size_t)(n_out+1)*16*2;
    unsigned short* C = (unsigned short*)p;  p += (size_t)(n_out+1)*64*2;
    unsigned short* D = (unsigned short*)p;  p += (size_t)(n_out+1)*16*2;
    unsigned short* E = (unsigned short*)p;  p += (size_t)(n_out+1)*16*2;
    unsigned short* Wf_c1 = (unsigned short*)p;  p += (size_t)32*4*512*2;
    unsigned short* Wf_00 = (unsigned short*)p;  p += (size_t)54*512*2;
    unsigned short* Wf_2  = (unsigned short*)p;  p += (size_t)54*512*2;
    unsigned short* Wf_01 = (unsigned short*)p;  p += (size_t)14*2*512*2;
    unsigned short* Wf_11 = (unsigned short*)p;  p += (size_t)14*512*2;
    unsigned short* Wf_10 = (unsigned short*)p;  p += (size_t)2*512*2;
    unsigned short* Wf_12 = (unsigned short*)p;  p += (size_t)2*512*2;
    float* OUT = (float*)d_out;

    auto cdiv = [](long a, long b){ return (int)((a + b - 1)/b); };

    // inverse kernel maps.
    // inv3 sentinel = n_out (zero-row trick; in3 values are in [0, n_out)).
    // inv1 sentinel = -1 (in1 values are in [0, n_in), n_in > n_out — n_out is a VALID index!).
    inv_init<<<cdiv((long)28*n_out,256),256,0,stream>>>(inv3, (long)28*n_out, n_out);
    inv_init<<<cdiv((long)8*n_out,256),256,0,stream>>>(inv1, (long)8*n_out, -1);
    inv_build<<<dim3(cdiv(M3,256),27),256,0,stream>>>(in3, out3, inv3, M3, n_out);
    inv_build<<<dim3(cdiv(M1,256),8),256,0,stream>>>(in1, out1, inv1, M1, n_out);
    zero_rows<<<1,256,0,stream>>>(A, B, C, D, E, n_out);

    // weight fragment conversion
    wfrag_unpaired<<<cdiv(32*4*512,256),256,0,stream>>>(W1,   Wf_c1, 4, 4, 128, 64, 32*4*512);
    wfrag_unpaired<<<cdiv(54*512,256),  256,0,stream>>>(Wr00, Wf_00, 2, 1,  64, 16, 54*512);
    wfrag_unpaired<<<cdiv(54*512,256),  256,0,stream>>>(W2,   Wf_2,  2, 1,  64,  8, 54*512);
    wfrag_unpaired<<<cdiv(2*512,256),   256,0,stream>>>(Wr10, Wf_10, 2, 1,  64, 16, 2*512);
    wfrag_paired  <<<cdiv(14*2*512,256),256,0,stream>>>(Wr01, Wf_01, 27, 2, 32, 14*2*512);
    wfrag_paired  <<<cdiv(14*512,256),  256,0,stream>>>(Wr11, Wf_11, 27, 1, 16, 14*512);
    wfrag_paired  <<<cdiv(2*512,256),   256,0,stream>>>(Wr12, Wf_12,  1, 2, 32, 2*512);

    const int grid_g = cdiv(n_out, 128);   // 4 waves/block, 32 rows/wave
    const int grid_d = cdiv(n_out, 64);    // 4 waves/block, 16 rows/wave

    // conv1: A = bf16( b1 + sum_k [xF|ctxF][inv1[k]] @ W1[k] )   (GB=1: 16 float4 loads/batch)
    mfma_gather<4, 8,1,4,4, 0, false, -1, true, 64, 0, 64, 3>
        <<<grid_g,256,0,stream>>>(nullptr, xF, ctxF, Wf_c1, inv1, b1, nullptr, A, n_out);
    // B = relu(sconv(A, Wr00) + br00)   (GB=5: 20 bf16x8 loads/batch)
    mfma_gather<0, 27,5,2,1, 128, true, -1, true, 16, 0, 16, 3>
        <<<grid_g,256,0,stream>>>(A, nullptr, nullptr, Wf_00, inv3, br00, nullptr, B, n_out);
    // D = relu(A @ Wr10 + br10)
    mfma_dense<2, 1, 128, true, -1, true, 16, 0, 16>
        <<<grid_d,256,0,stream>>>(A, Wf_10, br10, nullptr, D, n_out);
    // C[:,0:32] = sconv(B, Wr01) + br01 + A[:,0:32]   (GB=7: 14 loads/batch)
    mfma_gather<1, 14,7,1,2, 32, false, 0, true, 64, 0, 32, 3>
        <<<grid_g,256,0,stream>>>(B, nullptr, nullptr, Wf_01, inv3, br01, A, C, n_out);
    // E = relu(sconv(D, Wr11) + br11)
    mfma_gather<1, 14,7,1,1, 32, true, -1, true, 16, 0, 16, 3>
        <<<grid_g,256,0,stream>>>(D, nullptr, nullptr, Wf_11, inv3, br11, nullptr, E, n_out);
    // C[:,32:64] = E @ Wr12 + br12 + A[:,32:64]
    mfma_dense<3, 2, 32, false, 32, true, 64, 32, 32>
        <<<grid_d,256,0,stream>>>(E, Wf_12, br12, A, C, n_out);
    // OUT = sconv(C, W2) + b2   (fp32, masked to 8 cols)
    mfma_gather<0, 27,5,2,1, 128, false, -1, false, 8, 0, 8, 3>
        <<<grid_g,256,0,stream>>>(C, nullptr, nullptr, Wf_2, inv3, b2, nullptr, OUT, n_out);
}

// Round 9
// 329.540 us; speedup vs baseline: 1.2002x; 1.2002x over previous
//
#include <hip/hip_runtime.h>

#define DEV __device__ __forceinline__

typedef __attribute__((ext_vector_type(8))) short bf16x8;
typedef __attribute__((ext_vector_type(4))) float f32x4;

DEV float4 ld4(const float* p){ return *reinterpret_cast<const float4*>(p); }

DEV unsigned short f2bf(float f){
    union { float f; unsigned u; } v; v.f = f;
    unsigned r = v.u + 0x7fffu + ((v.u >> 16) & 1u);   // RNE
    return (unsigned short)(r >> 16);
}
DEV float bf2f(unsigned short s){
    union { unsigned u; float f; } v; v.u = ((unsigned)s) << 16;
    return v.f;
}

// async global->LDS, 16B/lane: LDS dest is wave-uniform base + lane*16,
// global SOURCE is per-lane (the gather!).  [m97/m173 pattern]
DEV void async16(const void* g, void* l){
    __builtin_amdgcn_global_load_lds(
        (const __attribute__((address_space(1))) unsigned*)g,
        (__attribute__((address_space(3))) unsigned*)l, 16, 0, 0);
}

// bijective XCD-chunk swizzle (m204)
DEV int xcd_swizzle(int orig, int nwg){
    int q = nwg >> 3, r = nwg & 7;
    int x = orig & 7, i = orig >> 3;
    return (x < r ? x*(q+1) : r*(q+1) + (x-r)*q) + i;
}

// ---------------- inverse kernel-map build ----------------
__global__ __launch_bounds__(256)
void inv_init(int* __restrict__ inv, long n, int defv){
    long i = (long)blockIdx.x*256 + threadIdx.x;
    if (i < n) inv[i] = defv;
}

__global__ __launch_bounds__(256)
void inv_build(const int* __restrict__ inK, const int* __restrict__ outK,
               int* __restrict__ inv, int M, int n_out){
    int k = blockIdx.y;
    int m = blockIdx.x*256 + threadIdx.x;
    if (m >= M) return;
    int o = outK[(long)k*M + m];
    if (o != n_out) inv[(long)k*n_out + o] = inK[(long)k*M + m];  // o unique per offset
}

// zero sentinel rows (row n_out) of bf16 feature buffers
__global__ __launch_bounds__(256)
void zero_rows(unsigned short* A, unsigned short* B, unsigned short* C,
               unsigned short* D, unsigned short* E, int n_out){
    int t = threadIdx.x;
    if (t < 64)       A[(long)n_out*64 + t] = 0;
    else if (t < 80)  B[(long)n_out*16 + (t-64)] = 0;
    else if (t < 144) C[(long)n_out*64 + (t-80)] = 0;
    else if (t < 160) D[(long)n_out*16 + (t-144)] = 0;
    else if (t < 176) E[(long)n_out*16 + (t-160)] = 0;
}

// ---------------- W -> fragment-layout bf16 conversion ----------------
__global__ __launch_bounds__(256)
void wfrag_unpaired(const float* __restrict__ W, unsigned short* __restrict__ F,
                    int KC, int NT, int CIN, int CR, int total){
    int idx = blockIdx.x*256 + threadIdx.x;
    if (idx >= total) return;
    int j = idx & 7, l = (idx >> 3) & 63, rest = idx >> 9;
    int nt = rest % NT, cc = rest / NT;
    int k = cc / KC, kc = cc % KC;
    int g = l >> 4, c = l & 15;
    int cin = kc*32 + g*8 + j, cout = nt*16 + c;
    float v = (cout < CR) ? W[((long)k*CIN + cin)*CR + cout] : 0.f;
    F[idx] = f2bf(v);
}

__global__ __launch_bounds__(256)
void wfrag_paired(const float* __restrict__ W, unsigned short* __restrict__ F,
                  int NKr, int NT, int CR, int total){
    int idx = blockIdx.x*256 + threadIdx.x;
    if (idx >= total) return;
    int j = idx & 7, l = (idx >> 3) & 63, rest = idx >> 9;
    int nt = rest % NT, cc = rest / NT;
    int g = l >> 4, c = l & 15;
    int koff = 2*cc + (g >> 1);
    int cin = (g & 1)*8 + j, cout = nt*16 + c;
    float v = (koff < NKr && cout < CR) ? W[((long)koff*16 + cin)*CR + cout] : 0.f;
    F[idx] = f2bf(v);
}

// ---------------- LDS-staged 27-offset gather conv (CIN=64, NT=1) ----------------
// Block = 4 waves = 64 rows. Double-buffered LDS (2 x 8KB). Per k: each wave issues
// 2 x global_load_lds (per-lane GATHERED source, swizzled col) for tile k+1, prefetches
// idx(k+2) + W(k+1) into regs, computes tile k (2 ds_read_b128 + 2 MFMA), barrier.
// Barrier drain (vmcnt0) provides DMA->ds_read ordering; TLP (~32 waves/CU) hides it.
template<bool RELU, bool OUTBF16, int YS, int CR>
__global__ __launch_bounds__(256)
void gather27_lds(const void* __restrict__ Xv, const unsigned short* __restrict__ Wf,
                  const int* __restrict__ inv, const float* __restrict__ bias,
                  void* __restrict__ Yv, int n_out)
{
    __shared__ alignas(16) char buf[2*8192];
    const int lane = threadIdx.x & 63, w = threadIdx.x >> 6;
    const long jblock = (long)blockIdx.x * 64;
    if (jblock >= n_out) return;
    const int r = lane & 15, g = lane >> 4;
    const char* X = (const char*)Xv;
    const bf16x8* __restrict__ WF = (const bf16x8*)Wf;

    // staging geometry: issue i covers LDS rows w*16+i*8+(l>>3); src col pre-swizzled
    const int  scol = (((lane & 7) ^ (lane >> 3)) << 4);
    const long jr0 = min(jblock + w*16 +     (lane >> 3), (long)n_out - 1);
    const long jr1 = min(jblock + w*16 + 8 + (lane >> 3), (long)n_out - 1);
    char* lds_w0 = buf + w*2048;            // issue 0 dest (uniform per wave)
    char* lds_w1 = buf + w*2048 + 1024;     // issue 1 dest

    // A-frag read addresses (lane r,g; kc 0/1), XOR-swizzled
    const int rd0 = w*2048 + r*128 + (( 0 + g*16) ^ ((r & 7) << 4));
    const int rd1 = w*2048 + r*128 + ((64 + g*16) ^ ((r & 7) << 4));

    f32x4 acc = {0,0,0,0};

    // prologue: stage k=0 into buf0; prefetch idx(k=1) + W(k=0)
    int c0 = inv[jr0], c1 = inv[jr1];
    async16(X + (long)c0*128 + scol, lds_w0);
    async16(X + (long)c1*128 + scol, lds_w1);
    int n0 = inv[(long)n_out + jr0], n1 = inv[(long)n_out + jr1];
    bf16x8 wc0 = WF[lane], wc1 = WF[64 + lane];
    __syncthreads();

    #pragma unroll 1
    for (int k = 0; k < 27; ++k){
        const int cb = k & 1;
        if (k < 26){
            char* dst = buf + (cb^1)*8192 + w*2048;
            async16(X + (long)n0*128 + scol, dst);
            async16(X + (long)n1*128 + scol, dst + 1024);
        }
        int t0 = 0, t1 = 0;
        if (k < 25){
            t0 = inv[(long)(k+2)*n_out + jr0];
            t1 = inv[(long)(k+2)*n_out + jr1];
        }
        bf16x8 wn0 = wc0, wn1 = wc1;
        if (k < 26){
            wn0 = WF[((long)(k+1)*2    )*64 + lane];
            wn1 = WF[((long)(k+1)*2 + 1)*64 + lane];
        }
        // compute tile k from buf[cb]
        bf16x8 a0 = *(const bf16x8*)(buf + cb*8192 + rd0);
        bf16x8 a1 = *(const bf16x8*)(buf + cb*8192 + rd1);
        acc = __builtin_amdgcn_mfma_f32_16x16x32_bf16(a0, wc0, acc, 0, 0, 0);
        acc = __builtin_amdgcn_mfma_f32_16x16x32_bf16(a1, wc1, acc, 0, 0, 0);
        __syncthreads();    // drains DMA (k+1 ready), idx, W prefetch
        n0 = t0; n1 = t1; wc0 = wn0; wc1 = wn1;
    }

    // epilogue: D layout col = lane&15, row = (lane>>4)*4 + q
    const float bv = (r < CR) ? bias[r] : 0.f;
    #pragma unroll
    for (int q = 0; q < 4; ++q){
        long row = jblock + w*16 + g*4 + q;
        if (row < n_out){
            float v = acc[q] + bv;
            if constexpr (RELU) v = fmaxf(v, 0.f);
            if constexpr (OUTBF16) ((unsigned short*)Yv)[row*YS + r] = f2bf(v);
            else if (r < CR)       ((float*)Yv)[row*YS + r] = v;
        }
    }
}

// ---------------- conv1 (round-6 MODE 4 form, validated) ----------------
// 2 tiles/wave (32 rows); 8 offsets, idx preloaded; masked fp32 loads + cvt; bias in epilogue.
__global__ __launch_bounds__(256, 3)
void conv1_g(const float* __restrict__ xF, const float* __restrict__ cF,
             const unsigned short* __restrict__ Wf, const int* __restrict__ inv,
             const float* __restrict__ bias, unsigned short* __restrict__ Y, int n_out)
{
    const int bid = xcd_swizzle(blockIdx.x, gridDim.x);
    const int lane = threadIdx.x & 63, wave = threadIdx.x >> 6;
    const int jbase = (bid*4 + wave)*32;
    if (jbase >= n_out) return;
    const int r = lane & 15, g = lane >> 4;
    const int jc0 = min(jbase + r, n_out-1), jc1 = min(jbase + 16 + r, n_out-1);
    const bf16x8 az = {0,0,0,0,0,0,0,0};
    f32x4 acc0[4], acc1[4];
    #pragma unroll
    for (int nt=0; nt<4; ++nt){ acc0[nt] = f32x4{0,0,0,0}; acc1[nt] = f32x4{0,0,0,0}; }

    int b0[8], b1[8];
    #pragma unroll
    for (int kk=0; kk<8; ++kk){
        b0[kk] = inv[(long)kk*n_out + jc0];
        b1[kk] = inv[(long)kk*n_out + jc1];
    }
    #pragma unroll
    for (int kk=0; kk<8; ++kk){
        #pragma unroll
        for (int kc=0; kc<4; ++kc){
            bf16x8 a0 = az, a1 = az;
            if (b0[kk] >= 0){
                const float* s = (kc < 2) ? (xF + (long)b0[kk]*64 + kc*32 + g*8)
                                          : (cF + (long)b0[kk]*64 + (kc-2)*32 + g*8);
                float4 lo = ld4(s), hi = ld4(s+4);
                a0[0]=(short)f2bf(lo.x); a0[1]=(short)f2bf(lo.y);
                a0[2]=(short)f2bf(lo.z); a0[3]=(short)f2bf(lo.w);
                a0[4]=(short)f2bf(hi.x); a0[5]=(short)f2bf(hi.y);
                a0[6]=(short)f2bf(hi.z); a0[7]=(short)f2bf(hi.w);
            }
            if (b1[kk] >= 0){
                const float* s = (kc < 2) ? (xF + (long)b1[kk]*64 + kc*32 + g*8)
                                          : (cF + (long)b1[kk]*64 + (kc-2)*32 + g*8);
                float4 lo = ld4(s), hi = ld4(s+4);
                a1[0]=(short)f2bf(lo.x); a1[1]=(short)f2bf(lo.y);
                a1[2]=(short)f2bf(lo.z); a1[3]=(short)f2bf(lo.w);
                a1[4]=(short)f2bf(hi.x); a1[5]=(short)f2bf(hi.y);
                a1[6]=(short)f2bf(hi.z); a1[7]=(short)f2bf(hi.w);
            }
            #pragma unroll
            for (int nt=0; nt<4; ++nt){
                bf16x8 wv = *(const bf16x8*)(Wf + (((long)(kk*4+kc)*4 + nt)*64 + lane)*8);
                acc0[nt] = __builtin_amdgcn_mfma_f32_16x16x32_bf16(a0, wv, acc0[nt], 0, 0, 0);
                acc1[nt] = __builtin_amdgcn_mfma_f32_16x16x32_bf16(a1, wv, acc1[nt], 0, 0, 0);
            }
        }
    }
    #pragma unroll
    for (int q=0; q<4; ++q){
        int row = jbase + g*4 + q;
        if (row < n_out){
            #pragma unroll
            for (int nt=0; nt<4; ++nt)
                Y[(long)row*64 + nt*16 + r] = f2bf(acc0[nt][q] + bias[nt*16 + r]);
        }
        int row2 = jbase + 16 + g*4 + q;
        if (row2 < n_out){
            #pragma unroll
            for (int nt=0; nt<4; ++nt)
                Y[(long)row2*64 + nt*16 + r] = f2bf(acc1[nt][q] + bias[nt*16 + r]);
        }
    }
}

// ---------------- paired inv-gather (CIN=16) — round-7 validated form ----------------
template<int NK, int G, int NT, int RB, bool RELU, int RESBASE,
         int YS, int CB, int CR, int WPE>
__global__ __launch_bounds__(256, WPE)
void mfma_g1(const void* __restrict__ Xv, const unsigned short* __restrict__ Wf,
             const int* __restrict__ inv, const float* __restrict__ bias,
             const unsigned short* __restrict__ RES, unsigned short* __restrict__ Y, int n_out)
{
    const int lane = threadIdx.x & 63, wave = threadIdx.x >> 6;
    const int jbase = (blockIdx.x*4 + wave)*32;
    if (jbase >= n_out) return;
    const int r = lane & 15, g = lane >> 4;
    const int jc0 = min(jbase + r, n_out-1), jc1 = min(jbase + 16 + r, n_out-1);
    const char* X = (const char*)Xv;
    const bf16x8* __restrict__ WF = (const bf16x8*)Wf;
    f32x4 acc0[NT], acc1[NT];
    #pragma unroll
    for (int nt=0; nt<NT; ++nt){ acc0[nt] = f32x4{0,0,0,0}; acc1[nt] = f32x4{0,0,0,0}; }

    #pragma unroll 1
    for (int g0 = 0; g0 < NK; g0 += G) {
        int b0[G], b1[G];
        #pragma unroll
        for (int kk=0; kk<G; ++kk){
            int koff = 2*(g0+kk) + (g >> 1);
            b0[kk] = inv[(long)koff*n_out + jc0];
            b1[kk] = inv[(long)koff*n_out + jc1];
        }
        #pragma unroll
        for (int kk=0; kk<G; ++kk){
            const int k = g0 + kk;
            bf16x8 a0 = *(const bf16x8*)(X + (long)b0[kk]*RB + (g&1)*16);
            bf16x8 a1 = *(const bf16x8*)(X + (long)b1[kk]*RB + (g&1)*16);
            #pragma unroll
            for (int nt=0; nt<NT; ++nt){
                bf16x8 wv = WF[((long)k*NT + nt)*64 + lane];
                acc0[nt] = __builtin_amdgcn_mfma_f32_16x16x32_bf16(a0, wv, acc0[nt], 0, 0, 0);
                acc1[nt] = __builtin_amdgcn_mfma_f32_16x16x32_bf16(a1, wv, acc1[nt], 0, 0, 0);
            }
        }
    }

    float bi[NT];
    #pragma unroll
    for (int nt=0; nt<NT; ++nt){
        int c = nt*16 + r;
        bi[nt] = (c < CR) ? bias[c] : 0.f;
    }
    #pragma unroll
    for (int q=0; q<4; ++q){
        int row = jbase + g*4 + q;
        if (row < n_out){
            #pragma unroll
            for (int nt=0; nt<NT; ++nt){
                int c = nt*16 + r;
                float v = acc0[nt][q] + bi[nt];
                if constexpr (RESBASE >= 0) v += bf2f(RES[(long)row*64 + RESBASE + c]);
                if constexpr (RELU) v = fmaxf(v, 0.f);
                Y[(long)row*YS + CB + c] = f2bf(v);
            }
        }
        int row2 = jbase + 16 + g*4 + q;
        if (row2 < n_out){
            #pragma unroll
            for (int nt=0; nt<NT; ++nt){
                int c = nt*16 + r;
                float v = acc1[nt][q] + bi[nt];
                if constexpr (RESBASE >= 0) v += bf2f(RES[(long)row2*64 + RESBASE + c]);
                if constexpr (RELU) v = fmaxf(v, 0.f);
                Y[(long)row2*YS + CB + c] = f2bf(v);
            }
        }
    }
}

// ---------------- identity-mode MFMA (dense 1x1s) — validated form ----------------
template<int MODE, int NT, int RB, bool RELU, int RESBASE, int YS, int CB, int CR>
__global__ __launch_bounds__(256)
void mfma_dense(const void* __restrict__ Xv, const unsigned short* __restrict__ Wf,
                const float* __restrict__ bias, const unsigned short* __restrict__ RES,
                unsigned short* __restrict__ Y, int n_out)
{
    const int lane = threadIdx.x & 63, wave = threadIdx.x >> 6;
    const int jbase = (blockIdx.x*4 + wave)*16;
    if (jbase >= n_out) return;
    const int r = lane & 15, g = lane >> 4;
    const int jrow = jbase + r;
    const bool rowok = jrow < n_out;
    const char* X = (const char*)Xv;
    const bf16x8* __restrict__ WF = (const bf16x8*)Wf;
    const bf16x8 az = {0,0,0,0,0,0,0,0};
    f32x4 acc[NT];
    #pragma unroll
    for (int nt=0; nt<NT; ++nt) acc[nt] = f32x4{0,0,0,0};

    if constexpr (MODE == 2) {
        #pragma unroll
        for (int kc=0; kc<2; ++kc){
            bf16x8 a = az;
            if (rowok) a = *(const bf16x8*)(X + (long)jrow*RB + kc*64 + g*16);
            #pragma unroll
            for (int nt=0; nt<NT; ++nt){
                bf16x8 wv = WF[((long)kc*NT + nt)*64 + lane];
                acc[nt] = __builtin_amdgcn_mfma_f32_16x16x32_bf16(a, wv, acc[nt], 0, 0, 0);
            }
        }
    } else {
        bf16x8 a = az;
        if (rowok && g < 2) a = *(const bf16x8*)(X + (long)jrow*RB + (g&1)*16);
        #pragma unroll
        for (int nt=0; nt<NT; ++nt){
            bf16x8 wv = WF[nt*64 + lane];
            acc[nt] = __builtin_amdgcn_mfma_f32_16x16x32_bf16(a, wv, acc[nt], 0, 0, 0);
        }
    }

    float bi[NT];
    #pragma unroll
    for (int nt=0; nt<NT; ++nt){
        int c = nt*16 + r;
        bi[nt] = (c < CR) ? bias[c] : 0.f;
    }
    #pragma unroll
    for (int q=0; q<4; ++q){
        int row = jbase + g*4 + q;
        if (row < n_out){
            #pragma unroll
            for (int nt=0; nt<NT; ++nt){
                int c = nt*16 + r;
                float v = acc[nt][q] + bi[nt];
                if constexpr (RESBASE >= 0) v += bf2f(RES[(long)row*64 + RESBASE + c]);
                if constexpr (RELU) v = fmaxf(v, 0.f);
                Y[(long)row*YS + CB + c] = f2bf(v);
            }
        }
    }
}

extern "C" void kernel_launch(void* const* d_in, const int* in_sizes, int n_in_cnt,
                              void* d_out, int out_size, void* d_ws, size_t ws_size,
                              hipStream_t stream)
{
    const float* xF   = (const float*)d_in[0];
    const float* ctxF = (const float*)d_in[1];
    const float* W1   = (const float*)d_in[2];
    const float* b1   = (const float*)d_in[3];
    const float* Wr00 = (const float*)d_in[4];
    const float* br00 = (const float*)d_in[5];
    const float* Wr01 = (const float*)d_in[6];
    const float* br01 = (const float*)d_in[7];
    const float* Wr10 = (const float*)d_in[8];
    const float* br10 = (const float*)d_in[9];
    const float* Wr11 = (const float*)d_in[10];
    const float* br11 = (const float*)d_in[11];
    const float* Wr12 = (const float*)d_in[12];
    const float* br12 = (const float*)d_in[13];
    const float* W2   = (const float*)d_in[14];
    const float* b2   = (const float*)d_in[15];
    const int* in1  = (const int*)d_in[16];
    const int* out1 = (const int*)d_in[17];
    const int* in3  = (const int*)d_in[18];
    const int* out3 = (const int*)d_in[19];

    const int n_out = out_size / 8;          // CL = 8
    const int M1 = in_sizes[16] / 8;
    const int M3 = in_sizes[18] / 27;

    char* p = (char*)d_ws;
    int* inv3 = (int*)p;                 p += (size_t)28*n_out*4;   // 27 rows + pad row (for koff=27)
    int* inv1 = (int*)p;                 p += (size_t)8*n_out*4;
    unsigned short* A = (unsigned short*)p;  p += (size_t)(n_out+1)*64*2;
    unsigned short* B = (unsigned short*)p;  p += (size_t)(n_out+1)*16*2;
    unsigned short* C = (unsigned short*)p;  p += (size_t)(n_out+1)*64*2;
    unsigned short* D = (unsigned short*)p;  p += (size_t)(n_out+1)*16*2;
    unsigned short* E = (unsigned short*)p;  p += (size_t)(n_out+1)*16*2;
    unsigned short* Wf_c1 = (unsigned short*)p;  p += (size_t)32*4*512*2;
    unsigned short* Wf_00 = (unsigned short*)p;  p += (size_t)54*512*2;
    unsigned short* Wf_2  = (unsigned short*)p;  p += (size_t)54*512*2;
    unsigned short* Wf_01 = (unsigned short*)p;  p += (size_t)14*2*512*2;
    unsigned short* Wf_11 = (unsigned short*)p;  p += (size_t)14*512*2;
    unsigned short* Wf_10 = (unsigned short*)p;  p += (size_t)2*512*2;
    unsigned short* Wf_12 = (unsigned short*)p;  p += (size_t)2*512*2;
    float* OUT = (float*)d_out;

    auto cdiv = [](long a, long b){ return (int)((a + b - 1)/b); };

    // inv3 sentinel = n_out (zero-row gather); inv1 sentinel = -1 (values in [0,n_in), n_in > n_out!)
    inv_init<<<cdiv((long)28*n_out,256),256,0,stream>>>(inv3, (long)28*n_out, n_out);
    inv_init<<<cdiv((long)8*n_out,256),256,0,stream>>>(inv1, (long)8*n_out, -1);
    inv_build<<<dim3(cdiv(M3,256),27),256,0,stream>>>(in3, out3, inv3, M3, n_out);
    inv_build<<<dim3(cdiv(M1,256),8),256,0,stream>>>(in1, out1, inv1, M1, n_out);
    zero_rows<<<1,256,0,stream>>>(A, B, C, D, E, n_out);

    // weight fragment conversion
    wfrag_unpaired<<<cdiv(32*4*512,256),256,0,stream>>>(W1,   Wf_c1, 4, 4, 128, 64, 32*4*512);
    wfrag_unpaired<<<cdiv(54*512,256),  256,0,stream>>>(Wr00, Wf_00, 2, 1,  64, 16, 54*512);
    wfrag_unpaired<<<cdiv(54*512,256),  256,0,stream>>>(W2,   Wf_2,  2, 1,  64,  8, 54*512);
    wfrag_unpaired<<<cdiv(2*512,256),   256,0,stream>>>(Wr10, Wf_10, 2, 1,  64, 16, 2*512);
    wfrag_paired  <<<cdiv(14*2*512,256),256,0,stream>>>(Wr01, Wf_01, 27, 2, 32, 14*2*512);
    wfrag_paired  <<<cdiv(14*512,256),  256,0,stream>>>(Wr11, Wf_11, 27, 1, 16, 14*512);
    wfrag_paired  <<<cdiv(2*512,256),   256,0,stream>>>(Wr12, Wf_12,  1, 2, 32, 2*512);

    const int grid_g = cdiv(n_out, 128);   // conv1 / paired: 32 rows/wave, 4 waves
    const int grid_l = cdiv(n_out, 64);    // LDS-staged: 64 rows/block
    const int grid_d = cdiv(n_out, 64);    // dense: 16 rows/wave

    // conv1: A = bf16( b1 + sum_k [xF|ctxF][inv1[k]] @ W1[k] )
    conv1_g<<<grid_g,256,0,stream>>>(xF, ctxF, Wf_c1, inv1, b1, A, n_out);
    // B = relu(sconv(A, Wr00) + br00)     [LDS-staged gather]
    gather27_lds<true, true, 16, 16>
        <<<grid_l,256,0,stream>>>(A, Wf_00, inv3, br00, B, n_out);
    // D = relu(A @ Wr10 + br10)
    mfma_dense<2, 1, 128, true, -1, 16, 0, 16>
        <<<grid_d,256,0,stream>>>(A, Wf_10, br10, nullptr, D, n_out);
    // C[:,0:32] = sconv(B, Wr01) + br01 + A[:,0:32]
    mfma_g1<14,7,2, 32, false, 0, 64, 0, 32, 4>
        <<<grid_g,256,0,stream>>>(B, Wf_01, inv3, br01, A, C, n_out);
    // E = relu(sconv(D, Wr11) + br11)
    mfma_g1<14,7,1, 32, true, -1, 16, 0, 16, 4>
        <<<grid_g,256,0,stream>>>(D, Wf_11, inv3, br11, nullptr, E, n_out);
    // C[:,32:64] = E @ Wr12 + br12 + A[:,32:64]
    mfma_dense<3, 2, 32, false, 32, 64, 32, 32>
        <<<grid_d,256,0,stream>>>(E, Wf_12, br12, A, C, n_out);
    // OUT = sconv(C, W2) + b2             [LDS-staged gather, fp32 out masked to 8 cols]
    gather27_lds<false, false, 8, 8>
        <<<grid_l,256,0,stream>>>(C, Wf_2, inv3, b2, OUT, n_out);
}

// Round 10
// 293.332 us; speedup vs baseline: 1.3483x; 1.1234x over previous
//
#include <hip/hip_runtime.h>

#define DEV __device__ __forceinline__

typedef __attribute__((ext_vector_type(8))) short bf16x8;
typedef __attribute__((ext_vector_type(4))) float f32x4;

DEV float4 ld4(const float* p){ return *reinterpret_cast<const float4*>(p); }

DEV unsigned short f2bf(float f){
    union { float f; unsigned u; } v; v.f = f;
    unsigned r = v.u + 0x7fffu + ((v.u >> 16) & 1u);   // RNE
    return (unsigned short)(r >> 16);
}
DEV float bf2f(unsigned short s){
    union { unsigned u; float f; } v; v.u = ((unsigned)s) << 16;
    return v.f;
}

// async global->LDS, 16B/lane: LDS dest is wave-uniform base + lane*16,
// global SOURCE is per-lane (the gather!).  [m97/m173 pattern]
DEV void async16(const void* g, void* l){
    __builtin_amdgcn_global_load_lds(
        (const __attribute__((address_space(1))) unsigned*)g,
        (__attribute__((address_space(3))) unsigned*)l, 16, 0, 0);
}

// ---------------- inverse kernel-map build ----------------
__global__ __launch_bounds__(256)
void inv_init(int* __restrict__ inv, long n, int defv){
    long i = (long)blockIdx.x*256 + threadIdx.x;
    if (i < n) inv[i] = defv;
}

__global__ __launch_bounds__(256)
void inv_build(const int* __restrict__ inK, const int* __restrict__ outK,
               int* __restrict__ inv, int M, int n_out){
    int k = blockIdx.y;
    int m = blockIdx.x*256 + threadIdx.x;
    if (m >= M) return;
    int o = outK[(long)k*M + m];
    if (o != n_out) inv[(long)k*n_out + o] = inK[(long)k*M + m];  // o unique per offset
}

// zero sentinel rows (row n_out) of bf16 feature buffers
__global__ __launch_bounds__(256)
void zero_rows(unsigned short* A, unsigned short* B, unsigned short* C,
               unsigned short* D, unsigned short* E, int n_out){
    int t = threadIdx.x;
    if (t < 64)       A[(long)n_out*64 + t] = 0;
    else if (t < 80)  B[(long)n_out*16 + (t-64)] = 0;
    else if (t < 144) C[(long)n_out*64 + (t-80)] = 0;
    else if (t < 160) D[(long)n_out*16 + (t-144)] = 0;
    else if (t < 176) E[(long)n_out*16 + (t-160)] = 0;
}

// A rows [0,n_out) pre-filled with bias (bf16) — RMW base for conv1 passes
__global__ __launch_bounds__(256)
void fill_bias_bf16(unsigned short* __restrict__ A, const float* __restrict__ b, long total){
    long i = (long)blockIdx.x*256 + threadIdx.x;
    if (i < total) A[i] = f2bf(b[i & 63]);
}

// ---------------- W -> fragment-layout bf16 conversion ----------------
__global__ __launch_bounds__(256)
void wfrag_unpaired(const float* __restrict__ W, unsigned short* __restrict__ F,
                    int KC, int NT, int CIN, int CR, int total){
    int idx = blockIdx.x*256 + threadIdx.x;
    if (idx >= total) return;
    int j = idx & 7, l = (idx >> 3) & 63, rest = idx >> 9;
    int nt = rest % NT, cc = rest / NT;
    int k = cc / KC, kc = cc % KC;
    int g = l >> 4, c = l & 15;
    int cin = kc*32 + g*8 + j, cout = nt*16 + c;
    float v = (cout < CR) ? W[((long)k*CIN + cin)*CR + cout] : 0.f;
    F[idx] = f2bf(v);
}

__global__ __launch_bounds__(256)
void wfrag_paired(const float* __restrict__ W, unsigned short* __restrict__ F,
                  int NKr, int NT, int CR, int total){
    int idx = blockIdx.x*256 + threadIdx.x;
    if (idx >= total) return;
    int j = idx & 7, l = (idx >> 3) & 63, rest = idx >> 9;
    int nt = rest % NT, cc = rest / NT;
    int g = l >> 4, c = l & 15;
    int koff = 2*cc + (g >> 1);
    int cin = (g & 1)*8 + j, cout = nt*16 + c;
    float v = (koff < NKr && cout < CR) ? W[((long)koff*16 + cin)*CR + cout] : 0.f;
    F[idx] = f2bf(v);
}

// ---------------- LDS-staged 27-offset gather conv (CIN=64, NT=1) — validated round 9 ----------------
template<bool RELU, bool OUTBF16, int YS, int CR>
__global__ __launch_bounds__(256)
void gather27_lds(const void* __restrict__ Xv, const unsigned short* __restrict__ Wf,
                  const int* __restrict__ inv, const float* __restrict__ bias,
                  void* __restrict__ Yv, int n_out)
{
    __shared__ alignas(16) char buf[2*8192];
    const int lane = threadIdx.x & 63, w = threadIdx.x >> 6;
    const long jblock = (long)blockIdx.x * 64;
    if (jblock >= n_out) return;
    const int r = lane & 15, g = lane >> 4;
    const char* X = (const char*)Xv;
    const bf16x8* __restrict__ WF = (const bf16x8*)Wf;

    const int  scol = (((lane & 7) ^ (lane >> 3)) << 4);
    const long jr0 = min(jblock + w*16 +     (lane >> 3), (long)n_out - 1);
    const long jr1 = min(jblock + w*16 + 8 + (lane >> 3), (long)n_out - 1);
    char* lds_w0 = buf + w*2048;
    char* lds_w1 = buf + w*2048 + 1024;

    const int rd0 = w*2048 + r*128 + (( 0 + g*16) ^ ((r & 7) << 4));
    const int rd1 = w*2048 + r*128 + ((64 + g*16) ^ ((r & 7) << 4));

    f32x4 acc = {0,0,0,0};

    int c0 = inv[jr0], c1 = inv[jr1];
    async16(X + (long)c0*128 + scol, lds_w0);
    async16(X + (long)c1*128 + scol, lds_w1);
    int n0 = inv[(long)n_out + jr0], n1 = inv[(long)n_out + jr1];
    bf16x8 wc0 = WF[lane], wc1 = WF[64 + lane];
    __syncthreads();

    #pragma unroll 1
    for (int k = 0; k < 27; ++k){
        const int cb = k & 1;
        if (k < 26){
            char* dst = buf + (cb^1)*8192 + w*2048;
            async16(X + (long)n0*128 + scol, dst);
            async16(X + (long)n1*128 + scol, dst + 1024);
        }
        int t0 = 0, t1 = 0;
        if (k < 25){
            t0 = inv[(long)(k+2)*n_out + jr0];
            t1 = inv[(long)(k+2)*n_out + jr1];
        }
        bf16x8 wn0 = wc0, wn1 = wc1;
        if (k < 26){
            wn0 = WF[((long)(k+1)*2    )*64 + lane];
            wn1 = WF[((long)(k+1)*2 + 1)*64 + lane];
        }
        bf16x8 a0 = *(const bf16x8*)(buf + cb*8192 + rd0);
        bf16x8 a1 = *(const bf16x8*)(buf + cb*8192 + rd1);
        acc = __builtin_amdgcn_mfma_f32_16x16x32_bf16(a0, wc0, acc, 0, 0, 0);
        acc = __builtin_amdgcn_mfma_f32_16x16x32_bf16(a1, wc1, acc, 0, 0, 0);
        __syncthreads();
        n0 = t0; n1 = t1; wc0 = wn0; wc1 = wn1;
    }

    const float bv = (r < CR) ? bias[r] : 0.f;
    #pragma unroll
    for (int q = 0; q < 4; ++q){
        long row = jblock + w*16 + g*4 + q;
        if (row < n_out){
            float v = acc[q] + bv;
            if constexpr (RELU) v = fmaxf(v, 0.f);
            if constexpr (OUTBF16) ((unsigned short*)Yv)[row*YS + r] = f2bf(v);
            else if (r < CR)       ((float*)Yv)[row*YS + r] = v;
        }
    }
}

// ---------------- conv1: compacted per-offset pass (gather -> MFMA -> scattered bf16 RMW) ----------------
// Work proportional to REAL pairs (~n_in/8 per pass). Outputs unique within a pass -> plain RMW.
// Pads: in1 = n_in -> zero A-frag; out1 = n_out -> dump to row n_out+1 (keeps zero-sentinel row clean).
__global__ __launch_bounds__(256)
void conv1_pass(const float* __restrict__ xF, const float* __restrict__ cF,
                const unsigned short* __restrict__ Wfk,   // Wf_c1 + k*16*512
                const int* __restrict__ in1k, const int* __restrict__ out1k,
                unsigned short* __restrict__ A, int M1, int n_in, int n_out)
{
    const int lane = threadIdx.x & 63, wave = threadIdx.x >> 6;
    const int m0 = (blockIdx.x*4 + wave)*16;
    if (m0 >= M1) return;
    const int r = lane & 15, g = lane >> 4;
    const int mc = min(m0 + r, M1-1);
    const int i = in1k[mc];
    const bool valid = i < n_in;             // pad sentinel = n_in
    const long iv = valid ? i : 0;
    const bf16x8* __restrict__ WF = (const bf16x8*)Wfk;
    const bf16x8 az = {0,0,0,0,0,0,0,0};
    f32x4 acc[4];
    #pragma unroll
    for (int nt=0; nt<4; ++nt) acc[nt] = f32x4{0,0,0,0};

    #pragma unroll
    for (int kc=0; kc<4; ++kc){
        const float* s = (kc < 2) ? (xF + iv*64 + kc*32 + g*8)
                                  : (cF + iv*64 + (kc-2)*32 + g*8);
        float4 lo = ld4(s), hi = ld4(s+4);
        bf16x8 a;
        a[0]=(short)f2bf(lo.x); a[1]=(short)f2bf(lo.y);
        a[2]=(short)f2bf(lo.z); a[3]=(short)f2bf(lo.w);
        a[4]=(short)f2bf(hi.x); a[5]=(short)f2bf(hi.y);
        a[6]=(short)f2bf(hi.z); a[7]=(short)f2bf(hi.w);
        if (!valid) a = az;
        #pragma unroll
        for (int nt=0; nt<4; ++nt){
            bf16x8 wv = WF[((long)kc*4 + nt)*64 + lane];
            acc[nt] = __builtin_amdgcn_mfma_f32_16x16x32_bf16(a, wv, acc[nt], 0, 0, 0);
        }
    }

    // D layout: col = lane&15, row-in-tile = g*4+q; RMW into A (bias pre-filled)
    #pragma unroll
    for (int q=0; q<4; ++q){
        int m = m0 + g*4 + q;
        if (m < M1){
            int o = out1k[m];                                   // broadcast per 16-lane group
            long row = (o == n_out) ? (long)n_out + 1 : (long)o;
            #pragma unroll
            for (int nt=0; nt<4; ++nt){
                long off = row*64 + nt*16 + r;
                A[off] = f2bf(acc[nt][q] + bf2f(A[off]));
            }
        }
    }
}

// ---------------- paired inv-gather (CIN=16) — validated form ----------------
template<int NK, int G, int NT, int RB, bool RELU, int RESBASE,
         int YS, int CB, int CR, int WPE>
__global__ __launch_bounds__(256, WPE)
void mfma_g1(const void* __restrict__ Xv, const unsigned short* __restrict__ Wf,
             const int* __restrict__ inv, const float* __restrict__ bias,
             const unsigned short* __restrict__ RES, unsigned short* __restrict__ Y, int n_out)
{
    const int lane = threadIdx.x & 63, wave = threadIdx.x >> 6;
    const int jbase = (blockIdx.x*4 + wave)*32;
    if (jbase >= n_out) return;
    const int r = lane & 15, g = lane >> 4;
    const int jc0 = min(jbase + r, n_out-1), jc1 = min(jbase + 16 + r, n_out-1);
    const char* X = (const char*)Xv;
    const bf16x8* __restrict__ WF = (const bf16x8*)Wf;
    f32x4 acc0[NT], acc1[NT];
    #pragma unroll
    for (int nt=0; nt<NT; ++nt){ acc0[nt] = f32x4{0,0,0,0}; acc1[nt] = f32x4{0,0,0,0}; }

    #pragma unroll 1
    for (int g0 = 0; g0 < NK; g0 += G) {
        int b0[G], b1[G];
        #pragma unroll
        for (int kk=0; kk<G; ++kk){
            int koff = 2*(g0+kk) + (g >> 1);
            b0[kk] = inv[(long)koff*n_out + jc0];
            b1[kk] = inv[(long)koff*n_out + jc1];
        }
        #pragma unroll
        for (int kk=0; kk<G; ++kk){
            const int k = g0 + kk;
            bf16x8 a0 = *(const bf16x8*)(X + (long)b0[kk]*RB + (g&1)*16);
            bf16x8 a1 = *(const bf16x8*)(X + (long)b1[kk]*RB + (g&1)*16);
            #pragma unroll
            for (int nt=0; nt<NT; ++nt){
                bf16x8 wv = WF[((long)k*NT + nt)*64 + lane];
                acc0[nt] = __builtin_amdgcn_mfma_f32_16x16x32_bf16(a0, wv, acc0[nt], 0, 0, 0);
                acc1[nt] = __builtin_amdgcn_mfma_f32_16x16x32_bf16(a1, wv, acc1[nt], 0, 0, 0);
            }
        }
    }

    float bi[NT];
    #pragma unroll
    for (int nt=0; nt<NT; ++nt){
        int c = nt*16 + r;
        bi[nt] = (c < CR) ? bias[c] : 0.f;
    }
    #pragma unroll
    for (int q=0; q<4; ++q){
        int row = jbase + g*4 + q;
        if (row < n_out){
            #pragma unroll
            for (int nt=0; nt<NT; ++nt){
                int c = nt*16 + r;
                float v = acc0[nt][q] + bi[nt];
                if constexpr (RESBASE >= 0) v += bf2f(RES[(long)row*64 + RESBASE + c]);
                if constexpr (RELU) v = fmaxf(v, 0.f);
                Y[(long)row*YS + CB + c] = f2bf(v);
            }
        }
        int row2 = jbase + 16 + g*4 + q;
        if (row2 < n_out){
            #pragma unroll
            for (int nt=0; nt<NT; ++nt){
                int c = nt*16 + r;
                float v = acc1[nt][q] + bi[nt];
                if constexpr (RESBASE >= 0) v += bf2f(RES[(long)row2*64 + RESBASE + c]);
                if constexpr (RELU) v = fmaxf(v, 0.f);
                Y[(long)row2*YS + CB + c] = f2bf(v);
            }
        }
    }
}

// ---------------- identity-mode MFMA (dense 1x1s) — validated form ----------------
template<int MODE, int NT, int RB, bool RELU, int RESBASE, int YS, int CB, int CR>
__global__ __launch_bounds__(256)
void mfma_dense(const void* __restrict__ Xv, const unsigned short* __restrict__ Wf,
                const float* __restrict__ bias, const unsigned short* __restrict__ RES,
                unsigned short* __restrict__ Y, int n_out)
{
    const int lane = threadIdx.x & 63, wave = threadIdx.x >> 6;
    const int jbase = (blockIdx.x*4 + wave)*16;
    if (jbase >= n_out) return;
    const int r = lane & 15, g = lane >> 4;
    const int jrow = jbase + r;
    const bool rowok = jrow < n_out;
    const char* X = (const char*)Xv;
    const bf16x8* __restrict__ WF = (const bf16x8*)Wf;
    const bf16x8 az = {0,0,0,0,0,0,0,0};
    f32x4 acc[NT];
    #pragma unroll
    for (int nt=0; nt<NT; ++nt) acc[nt] = f32x4{0,0,0,0};

    if constexpr (MODE == 2) {
        #pragma unroll
        for (int kc=0; kc<2; ++kc){
            bf16x8 a = az;
            if (rowok) a = *(const bf16x8*)(X + (long)jrow*RB + kc*64 + g*16);
            #pragma unroll
            for (int nt=0; nt<NT; ++nt){
                bf16x8 wv = WF[((long)kc*NT + nt)*64 + lane];
                acc[nt] = __builtin_amdgcn_mfma_f32_16x16x32_bf16(a, wv, acc[nt], 0, 0, 0);
            }
        }
    } else {
        bf16x8 a = az;
        if (rowok && g < 2) a = *(const bf16x8*)(X + (long)jrow*RB + (g&1)*16);
        #pragma unroll
        for (int nt=0; nt<NT; ++nt){
            bf16x8 wv = WF[nt*64 + lane];
            acc[nt] = __builtin_amdgcn_mfma_f32_16x16x32_bf16(a, wv, acc[nt], 0, 0, 0);
        }
    }

    float bi[NT];
    #pragma unroll
    for (int nt=0; nt<NT; ++nt){
        int c = nt*16 + r;
        bi[nt] = (c < CR) ? bias[c] : 0.f;
    }
    #pragma unroll
    for (int q=0; q<4; ++q){
        int row = jbase + g*4 + q;
        if (row < n_out){
            #pragma unroll
            for (int nt=0; nt<NT; ++nt){
                int c = nt*16 + r;
                float v = acc[nt][q] + bi[nt];
                if constexpr (RESBASE >= 0) v += bf2f(RES[(long)row*64 + RESBASE + c]);
                if constexpr (RELU) v = fmaxf(v, 0.f);
                Y[(long)row*YS + CB + c] = f2bf(v);
            }
        }
    }
}

extern "C" void kernel_launch(void* const* d_in, const int* in_sizes, int n_in_cnt,
                              void* d_out, int out_size, void* d_ws, size_t ws_size,
                              hipStream_t stream)
{
    const float* xF   = (const float*)d_in[0];
    const float* ctxF = (const float*)d_in[1];
    const float* W1   = (const float*)d_in[2];
    const float* b1   = (const float*)d_in[3];
    const float* Wr00 = (const float*)d_in[4];
    const float* br00 = (const float*)d_in[5];
    const float* Wr01 = (const float*)d_in[6];
    const float* br01 = (const float*)d_in[7];
    const float* Wr10 = (const float*)d_in[8];
    const float* br10 = (const float*)d_in[9];
    const float* Wr11 = (const float*)d_in[10];
    const float* br11 = (const float*)d_in[11];
    const float* Wr12 = (const float*)d_in[12];
    const float* br12 = (const float*)d_in[13];
    const float* W2   = (const float*)d_in[14];
    const float* b2   = (const float*)d_in[15];
    const int* in1  = (const int*)d_in[16];
    const int* out1 = (const int*)d_in[17];
    const int* in3  = (const int*)d_in[18];
    const int* out3 = (const int*)d_in[19];

    const int n_out = out_size / 8;          // CL = 8
    const int n_in  = in_sizes[0] / 64;
    const int M1 = in_sizes[16] / 8;
    const int M3 = in_sizes[18] / 27;

    char* p = (char*)d_ws;
    int* inv3 = (int*)p;                 p += (size_t)28*n_out*4;   // 27 rows + pad row (koff=27)
    unsigned short* A = (unsigned short*)p;  p += (size_t)(n_out+2)*64*2;  // +sentinel row, +pad-dump row
    unsigned short* B = (unsigned short*)p;  p += (size_t)(n_out+1)*16*2;
    unsigned short* C = (unsigned short*)p;  p += (size_t)(n_out+1)*64*2;
    unsigned short* D = (unsigned short*)p;  p += (size_t)(n_out+1)*16*2;
    unsigned short* E = (unsigned short*)p;  p += (size_t)(n_out+1)*16*2;
    unsigned short* Wf_c1 = (unsigned short*)p;  p += (size_t)32*4*512*2;
    unsigned short* Wf_00 = (unsigned short*)p;  p += (size_t)54*512*2;
    unsigned short* Wf_2  = (unsigned short*)p;  p += (size_t)54*512*2;
    unsigned short* Wf_01 = (unsigned short*)p;  p += (size_t)14*2*512*2;
    unsigned short* Wf_11 = (unsigned short*)p;  p += (size_t)14*512*2;
    unsigned short* Wf_10 = (unsigned short*)p;  p += (size_t)2*512*2;
    unsigned short* Wf_12 = (unsigned short*)p;  p += (size_t)2*512*2;
    float* OUT = (float*)d_out;

    auto cdiv = [](long a, long b){ return (int)((a + b - 1)/b); };

    // inv3 sentinel = n_out (zero-row gather). conv1 no longer needs an inverse map.
    inv_init<<<cdiv((long)28*n_out,256),256,0,stream>>>(inv3, (long)28*n_out, n_out);
    inv_build<<<dim3(cdiv(M3,256),27),256,0,stream>>>(in3, out3, inv3, M3, n_out);
    zero_rows<<<1,256,0,stream>>>(A, B, C, D, E, n_out);
    fill_bias_bf16<<<cdiv((long)n_out*64,256),256,0,stream>>>(A, b1, (long)n_out*64);

    // weight fragment conversion
    wfrag_unpaired<<<cdiv(32*4*512,256),256,0,stream>>>(W1,   Wf_c1, 4, 4, 128, 64, 32*4*512);
    wfrag_unpaired<<<cdiv(54*512,256),  256,0,stream>>>(Wr00, Wf_00, 2, 1,  64, 16, 54*512);
    wfrag_unpaired<<<cdiv(54*512,256),  256,0,stream>>>(W2,   Wf_2,  2, 1,  64,  8, 54*512);
    wfrag_unpaired<<<cdiv(2*512,256),   256,0,stream>>>(Wr10, Wf_10, 2, 1,  64, 16, 2*512);
    wfrag_paired  <<<cdiv(14*2*512,256),256,0,stream>>>(Wr01, Wf_01, 27, 2, 32, 14*2*512);
    wfrag_paired  <<<cdiv(14*512,256),  256,0,stream>>>(Wr11, Wf_11, 27, 1, 16, 14*512);
    wfrag_paired  <<<cdiv(2*512,256),   256,0,stream>>>(Wr12, Wf_12,  1, 2, 32, 2*512);

    // conv1: 8 compacted per-offset passes, bf16 RMW into bias-filled A (outputs unique per pass)
    for (int k=0; k<8; ++k){
        conv1_pass<<<cdiv(M1,64),256,0,stream>>>(
            xF, ctxF, Wf_c1 + (size_t)k*16*512,
            in1 + (size_t)k*M1, out1 + (size_t)k*M1, A, M1, n_in, n_out);
    }

    const int grid_g = cdiv(n_out, 128);   // paired: 32 rows/wave, 4 waves
    const int grid_l = cdiv(n_out, 64);    // LDS-staged: 64 rows/block
    const int grid_d = cdiv(n_out, 64);    // dense: 16 rows/wave

    // B = relu(sconv(A, Wr00) + br00)     [LDS-staged gather]
    gather27_lds<true, true, 16, 16>
        <<<grid_l,256,0,stream>>>(A, Wf_00, inv3, br00, B, n_out);
    // D = relu(A @ Wr10 + br10)
    mfma_dense<2, 1, 128, true, -1, 16, 0, 16>
        <<<grid_d,256,0,stream>>>(A, Wf_10, br10, nullptr, D, n_out);
    // C[:,0:32] = sconv(B, Wr01) + br01 + A[:,0:32]
    mfma_g1<14,7,2, 32, false, 0, 64, 0, 32, 4>
        <<<grid_g,256,0,stream>>>(B, Wf_01, inv3, br01, A, C, n_out);
    // E = relu(sconv(D, Wr11) + br11)
    mfma_g1<14,7,1, 32, true, -1, 16, 0, 16, 4>
        <<<grid_g,256,0,stream>>>(D, Wf_11, inv3, br11, nullptr, E, n_out);
    // C[:,32:64] = E @ Wr12 + br12 + A[:,32:64]
    mfma_dense<3, 2, 32, false, 32, 64, 32, 32>
        <<<grid_d,256,0,stream>>>(E, Wf_12, br12, A, C, n_out);
    // OUT = sconv(C, W2) + b2             [LDS-staged gather, fp32 out masked to 8 cols]
    gather27_lds<false, false, 8, 8>
        <<<grid_l,256,0,stream>>>(C, Wf_2, inv3, b2, OUT, n_out);
}